// Round 20
// baseline (97.387 us; speedup 1.0000x reference)
//
#include <hip/hip_runtime.h>
#include <hip/hip_bf16.h>

typedef __bf16 bf16x8 __attribute__((ext_vector_type(8)));
typedef float  f32x4  __attribute__((ext_vector_type(4)));
typedef float  f32x16 __attribute__((ext_vector_type(16)));

#define NB 16
#define NC 32
#define NH 32
#define NW 2048
#define NK (NC*NH)   // 1024
#define LOG2E 1.4426950408889634f

static __device__ __forceinline__ unsigned int pk2(float a, float b) {
    union { __bf16 h[2]; unsigned int u; } z;
    z.h[0] = (__bf16)a; z.h[1] = (__bf16)b;
    return z.u;
}

// ---------------------------------------------------------------------------
// Kernel 0: weights -> bf16. wb layout [3][32][1024]; wq scaled by log2e.
// ---------------------------------------------------------------------------
__global__ __launch_bounds__(256) void wprep_kernel(
    const float* __restrict__ wq, const float* __restrict__ wk,
    const float* __restrict__ wv, __bf16* __restrict__ wb)
{
    const int i = blockIdx.x * 256 + threadIdx.x;        // 24576 float4 units
    const float* srcs[3] = { wq, wk, wv };
    float4 v = *(const float4*)(srcs[i >> 13] + (size_t)(i & 8191) * 4);
    const float sc = (i >> 13) == 0 ? LOG2E : 1.0f;
    union { __bf16 h[4]; unsigned long long u; } z;
    z.h[0] = (__bf16)(v.x * sc); z.h[1] = (__bf16)(v.y * sc);
    z.h[2] = (__bf16)(v.z * sc); z.h[3] = (__bf16)(v.w * sc);
    *(unsigned long long*)(wb + (size_t)i * 4) = z.u;
}

// ---------------------------------------------------------------------------
// Kernel 1 (v9): QKV projection with global_load_lds DMA staging.
// 4 waves/block, wave = independent 256-k slice (8 steps x 32k), NO barriers
// in the main loop. Per step: 4 x global_load_lds(16B) DMA the 32k x 32w
// fp32 slab into the wave's private LDS region (linear dest = uniform base +
// lane*16; per-lane global src PRE-SWIZZLED chunk^=(row&7) so consumer
// column reads are 4-way-conflict ds_read_b32). Counted s_waitcnt vmcnt(10)
// (never 0 mid-loop) + sched_barrier(0). bf16 cvt at consume (16/step).
// B-frags reg-prefetched from bf16 wb. Two-round 24KB combine aliased over
// the 32KB staging LDS. Grid 1024 x 256 thr.
// ---------------------------------------------------------------------------
__global__ __launch_bounds__(256) void proj_kernel(
    const float* __restrict__ x, const __bf16* __restrict__ wb,
    const float* __restrict__ bq, const float* __restrict__ bk,
    const float* __restrict__ bv,
    __bf16* __restrict__ qT, __bf16* __restrict__ kT, __bf16* __restrict__ V)
{
    const int b    = blockIdx.x >> 6;
    const int wt   = blockIdx.x & 63;
    const int wave = threadIdx.x >> 6;       // = K slice 0..3
    const int lane = threadIdx.x & 63;
    const int g    = lane >> 4;
    const int lr   = lane & 15;
    const int w0   = wt * 32;

    __shared__ __align__(16) char smem[32768];   // 4 waves x 2 buf x 4KB
    f32x4 (*part)[6][64] = reinterpret_cast<f32x4(*)[6][64]>(smem);

    const float* xb = x + (size_t)b * NK * NW;
    const int k0 = wave * 256;

    // per-lane DMA source pieces: row-within-8 = lane>>3, chunk = lane&7
    const int drow = lane >> 3;              // 0..7
    const int dch  = (lane & 7) ^ drow;      // pre-swizzled source chunk
    const float* xsrc = xb + w0 + dch * 4;   // + k*NW per row

    char* wbase = smem + wave * 8192;        // this wave's staging region

    const __bf16* wrow = wb + (size_t)0;     // per-nt row computed below

    f32x4 acc[2][6];
    #pragma unroll
    for (int mt = 0; mt < 2; ++mt)
        #pragma unroll
        for (int nt = 0; nt < 6; ++nt)
            acc[mt][nt] = f32x4{0.f, 0.f, 0.f, 0.f};

    bf16x8 Bcur[6], Bnxt[6];

#define DMA(S)                                                                \
    { char* dst = wbase + ((S) & 1) * 4096;                                   \
      _Pragma("unroll")                                                       \
      for (int jc = 0; jc < 4; ++jc) {                                        \
          const float* gs = xsrc + (size_t)(k0 + (S)*32 + jc*8 + drow) * NW;  \
          __builtin_amdgcn_global_load_lds(                                   \
              (const __attribute__((address_space(1))) unsigned int*)gs,     \
              (__attribute__((address_space(3))) unsigned int*)(dst + jc*1024),\
              16, 0, 0);                                                      \
      } }

#define BLOAD(DST, S)                                                         \
    _Pragma("unroll")                                                         \
    for (int nt = 0; nt < 6; ++nt)                                            \
        DST[nt] = *(const bf16x8*)(wb + (size_t)(nt >> 1) * 32768             \
                                      + (size_t)((nt & 1) * 16 + lr) * NK     \
                                      + k0 + (S)*32 + g*8);

    // ---- prologue: DMA(0) + B(0) ----
    DMA(0);
    BLOAD(Bcur, 0);

    #pragma unroll
    for (int s = 0; s < 8; ++s) {
        if (s < 7) { DMA(s + 1); BLOAD(Bnxt, s + 1); }
        // counted drain: leave this iter's 10 (4 DMA + 6 B) in flight
        if (s < 7) asm volatile("s_waitcnt vmcnt(10)" ::: "memory");
        else       asm volatile("s_waitcnt vmcnt(0)"  ::: "memory");
        __builtin_amdgcn_sched_barrier(0);

        // consume buf[s&1]: 16 swizzled ds_read_b32 + cvt -> 2 A-frags
        const float* tb = (const float*)(wbase + (s & 1) * 4096);
        bf16x8 af[2];
        #pragma unroll
        for (int mt = 0; mt < 2; ++mt) {
            const int c = mt*4 + (lr >> 2);
            const int o = lr & 3;
            #pragma unroll
            for (int j = 0; j < 8; ++j) {
                const float v = tb[(g*8 + j)*32 + ((c ^ j) << 2) + o];
                af[mt][j] = (__bf16)v;
            }
        }
        #pragma unroll
        for (int nt = 0; nt < 6; ++nt) {
            acc[0][nt] = __builtin_amdgcn_mfma_f32_16x16x32_bf16(
                af[0], Bcur[nt], acc[0][nt], 0, 0, 0);
            acc[1][nt] = __builtin_amdgcn_mfma_f32_16x16x32_bf16(
                af[1], Bcur[nt], acc[1][nt], 0, 0, 0);
        }
        if (s < 7) {
            #pragma unroll
            for (int nt = 0; nt < 6; ++nt) Bcur[nt] = Bnxt[nt];
        }
    }
#undef DMA
#undef BLOAD

    // ---- combine the 4 K-slices, two mt-rounds, aliased LDS ----
    const float* biases[3] = { bq, bk, bv };
    #pragma unroll
    for (int mt = 0; mt < 2; ++mt) {
        __syncthreads();                     // staging dead / prev round done
        #pragma unroll
        for (int nt = 0; nt < 6; ++nt)
            part[wave][nt][lane] = acc[mt][nt];
        __syncthreads();
        #pragma unroll
        for (int q = 0; q < 2; ++q) {
            const int nt = wave + q * 4;
            if (nt < 6) {
                f32x4 s = part[0][nt][lane];
                #pragma unroll
                for (int sl = 1; sl < 4; ++sl) s += part[sl][nt][lane];
                const int pid = nt >> 1;             // 0=q,1=k,2=v
                const int o   = (nt & 1) * 16 + lr;
                float bb = biases[pid][o];
                if (pid == 0) bb *= LOG2E;
                if (pid < 2) {
                    __bf16* dst = (pid ? kT : qT) + (size_t)b * NW * NC;
                    #pragma unroll
                    for (int r = 0; r < 4; ++r) {
                        const int w = w0 + mt*16 + g*4 + r;
                        dst[(size_t)w * NC + o] = (__bf16)(s[r] + bb);
                    }
                } else {
                    union { __bf16 h[4]; unsigned long long u; } z;
                    #pragma unroll
                    for (int r = 0; r < 4; ++r) z.h[r] = (__bf16)(s[r] + bb);
                    __bf16* dst = V + ((size_t)b * NC + o) * NW + (w0 + mt*16 + g*4);
                    *(unsigned long long*)dst = z.u;
                }
            }
        }
    }
}

// ---------------------------------------------------------------------------
// Kernel 2: flash attention (R10/R14, unchanged/verified): fixed-max softmax,
// sigma-permuted K rows (lane-local PV fragments), software-pipelined loop,
// exp2 via __builtin_amdgcn_exp2f, NT out stores.
// ---------------------------------------------------------------------------
__global__ __launch_bounds__(256) void attn_kernel(
    const float* __restrict__ x,
    const __bf16* __restrict__ qT, const __bf16* __restrict__ kT,
    const __bf16* __restrict__ V,
    float* __restrict__ out)
{
    const int b    = blockIdx.x >> 6;
    const int wt   = blockIdx.x & 63;
    const int w0   = wt * 32;
    const int wave = threadIdx.x >> 6;        // KV slice 0..3
    const int lane = threadIdx.x & 63;
    const int wl = lane & 31, hi = lane >> 5;
    const int swl = (wl & 0x13) | ((wl & 4) << 1) | ((wl & 8) >> 1);

    const __bf16* qTb = qT + (size_t)b * NW * NC;
    const __bf16* kTb = kT + (size_t)b * NW * NC;
    const __bf16* Vb  = V  + (size_t)b * NC * NW;

    const __bf16* qrow = qTb + (size_t)(w0 + wl) * NC;
    const bf16x8 qf0 = *(const bf16x8*)(qrow + hi*8);
    const bf16x8 qf1 = *(const bf16x8*)(qrow + 16 + hi*8);

    f32x16 acc, z16;
    #pragma unroll
    for (int r = 0; r < 16; ++r) { acc[r] = 0.f; z16[r] = 0.f; }
    float lsum = 0.f;

    const int vbeg = wave * 512;
    const __bf16* kbase = kTb + (size_t)swl * NC;
    const __bf16* vbase = Vb + (size_t)wl * NW;

#define KLD0(V0) (*(const bf16x8*)(kbase + (size_t)(V0) * NC + hi*8))
#define KLD1(V0) (*(const bf16x8*)(kbase + (size_t)(V0) * NC + 16 + hi*8))
#define VLD0(V0) (*(const bf16x8*)(vbase + (V0) + hi*8))
#define VLD1(V0) (*(const bf16x8*)(vbase + (V0) + 16 + hi*8))

    bf16x8 k0r = KLD0(vbeg), k1r = KLD1(vbeg);
    f32x16 s_cur = __builtin_amdgcn_mfma_f32_32x32x16_bf16(k0r, qf0, z16, 0, 0, 0);
    s_cur = __builtin_amdgcn_mfma_f32_32x32x16_bf16(k1r, qf1, s_cur, 0, 0, 0);
    k0r = KLD0(vbeg + 32); k1r = KLD1(vbeg + 32);
    bf16x8 v0r = VLD0(vbeg), v1r = VLD1(vbeg);

    #pragma unroll
    for (int it = 0; it < 16; ++it) {
        f32x16 s_next;
        if (it < 15) {
            s_next = __builtin_amdgcn_mfma_f32_32x32x16_bf16(k0r, qf0, z16, 0, 0, 0);
            s_next = __builtin_amdgcn_mfma_f32_32x32x16_bf16(k1r, qf1, s_next, 0, 0, 0);
        }
        if (it < 14) {
            const int vn = vbeg + (it + 2) * 32;
            k0r = KLD0(vn); k1r = KLD1(vn);
        }

        float p[16];
        #pragma unroll
        for (int r = 0; r < 16; ++r) p[r] = __builtin_amdgcn_exp2f(s_cur[r]);
        float ts[8];
        #pragma unroll
        for (int r = 0; r < 8; ++r) ts[r] = p[r] + p[r+8];
        #pragma unroll
        for (int r = 0; r < 4; ++r) ts[r] += ts[r+4];
        lsum += (ts[0] + ts[1]) + (ts[2] + ts[3]);

        union { unsigned int u[4]; bf16x8 v; } pfa, pfb;
        #pragma unroll
        for (int i = 0; i < 4; ++i) pfa.u[i] = pk2(p[2*i],     p[2*i + 1]);
        #pragma unroll
        for (int i = 0; i < 4; ++i) pfb.u[i] = pk2(p[8 + 2*i], p[8 + 2*i + 1]);

        acc = __builtin_amdgcn_mfma_f32_32x32x16_bf16(v0r, pfa.v, acc, 0, 0, 0);
        acc = __builtin_amdgcn_mfma_f32_32x32x16_bf16(v1r, pfb.v, acc, 0, 0, 0);

        if (it < 15) {
            const int vn = vbeg + (it + 1) * 32;
            v0r = VLD0(vn); v1r = VLD1(vn);
            s_cur = s_next;
        }
    }
#undef KLD0
#undef KLD1
#undef VLD0
#undef VLD1
    lsum += __shfl_xor(lsum, 32);

    __shared__ float sl[4][32];
    __shared__ float sO[4][32][33];
    __shared__ float Of[32][33];

    if (hi == 0) sl[wave][wl] = lsum;
    #pragma unroll
    for (int r = 0; r < 16; ++r) {
        const int c = (r & 3) + 8*(r >> 2) + 4*hi;
        sO[wave][c][wl] = acc[r];
    }
    __syncthreads();

    {
        const int w  = threadIdx.x & 31;
        const int cg = threadIdx.x >> 5;
        const float L = (sl[0][w] + sl[1][w]) + (sl[2][w] + sl[3][w]);
        const float rL = 1.0f / L;
        #pragma unroll
        for (int cc = 0; cc < 4; ++cc) {
            const int c = cg * 4 + cc;
            const float o = ((sO[0][c][w] + sO[1][c][w]) +
                             (sO[2][c][w] + sO[3][c][w]));
            Of[c][w] = o * rL;
        }
    }
    __syncthreads();

    const float* xb = x   + (size_t)b * NC * NH * NW + w0;
    float*       ob = out + (size_t)b * NC * NH * NW + w0;
    const int chunk = threadIdx.x & 7;
    #pragma unroll
    for (int it = 0; it < 32; ++it) {
        const int row = it*32 + (threadIdx.x >> 3);
        const int c = row >> 5, h = row & 31;
        const size_t off = ((size_t)c * NH + h) * NW + chunk*4;
        const f32x4 xv = *(const f32x4*)(xb + off);
        f32x4 ov;
        ov[0] = Of[c][chunk*4 + 0] + xv[0];
        ov[1] = Of[c][chunk*4 + 1] + xv[1];
        ov[2] = Of[c][chunk*4 + 2] + xv[2];
        ov[3] = Of[c][chunk*4 + 3] + xv[3];
        __builtin_nontemporal_store(ov, (f32x4*)(ob + off));
    }
}

extern "C" void kernel_launch(void* const* d_in, const int* in_sizes, int n_in,
                              void* d_out, int out_size, void* d_ws, size_t ws_size,
                              hipStream_t stream)
{
    const float* x  = (const float*)d_in[0];
    const float* wq = (const float*)d_in[1];
    const float* bq = (const float*)d_in[2];
    const float* wk = (const float*)d_in[3];
    const float* bk = (const float*)d_in[4];
    const float* wv = (const float*)d_in[5];
    const float* bv = (const float*)d_in[6];
    float* out = (float*)d_out;

    // ws layout (bf16): qT [B][W][32] @0, kT @2MB, V [B][32][W] @4MB, wb @6MB
    char* ws = (char*)d_ws;
    __bf16* qT = (__bf16*)(ws);
    __bf16* kT = (__bf16*)(ws + (2u << 20));
    __bf16* V  = (__bf16*)(ws + (4u << 20));
    __bf16* wb = (__bf16*)(ws + (6u << 20));

    hipLaunchKernelGGL(wprep_kernel, dim3(96), dim3(256), 0, stream, wq, wk, wv, wb);
    hipLaunchKernelGGL(proj_kernel, dim3(NB * 64), dim3(256), 0, stream,
                       x, wb, bq, bk, bv, qT, kT, V);
    hipLaunchKernelGGL(attn_kernel, dim3(NB * 64), dim3(256), 0, stream,
                       x, qT, kT, V, out);
}